// Round 1
// baseline (3545.565 us; speedup 1.0000x reference)
//
#include <hip/hip_runtime.h>
#include <hip/hip_bf16.h>
#include <stdint.h>

// BitLinear: out = x @ (sign(W)*(|W|>0.7*mean|W|)*scale)^T
// M=16384 (8*2048), K=4096, N=16384. All f32 in/out.
// Plan: ternary-quantize W into bf16 bit patterns (exact), cast x to bf16 (RNE),
// run bf16-MFMA GEMM (m97 structure: 128x128 tile, BK=64, global_load_lds w16).

typedef __attribute__((ext_vector_type(8))) __bf16 bf16x8;
typedef __attribute__((ext_vector_type(4))) float f32x4;
typedef __attribute__((ext_vector_type(8))) unsigned short u16x8;

#define M_ROWS 16384
#define K_DIM  4096
#define N_DIM  16384

#define RED_BLOCKS 2048

// ---------- kernel 1a: per-block partial sums of |W| (deterministic) ----------
__global__ void absum_part_kernel(const float4* __restrict__ W4,
                                  double* __restrict__ part, long long n4) {
  double s = 0.0;
  const long long stride = (long long)gridDim.x * blockDim.x;
  for (long long i = (long long)blockIdx.x * blockDim.x + threadIdx.x; i < n4; i += stride) {
    float4 v = W4[i];
    s += (double)fabsf(v.x);
    s += (double)fabsf(v.y);
    s += (double)fabsf(v.z);
    s += (double)fabsf(v.w);
  }
  for (int o = 32; o > 0; o >>= 1) s += __shfl_down(s, o, 64);
  __shared__ double p[4];
  if ((threadIdx.x & 63) == 0) p[threadIdx.x >> 6] = s;
  __syncthreads();
  if (threadIdx.x == 0) part[blockIdx.x] = p[0] + p[1] + p[2] + p[3];
}

// ---------- kernel 1b: reduce partials -> total sum (single block, deterministic) ----------
__global__ void reduce_sum_kernel(const double* __restrict__ part,
                                  double* __restrict__ sum, int n) {
  double s = 0.0;
  for (int i = threadIdx.x; i < n; i += blockDim.x) s += part[i];
  for (int o = 32; o > 0; o >>= 1) s += __shfl_down(s, o, 64);
  __shared__ double p[4];
  if ((threadIdx.x & 63) == 0) p[threadIdx.x >> 6] = s;
  __syncthreads();
  if (threadIdx.x == 0) *sum = p[0] + p[1] + p[2] + p[3];
}

// ---------- kernel 2: ternary-quantize W -> bf16 bit patterns ----------
__device__ __forceinline__ unsigned short tern_bf16(float w, float thr) {
  // sign(w) * (|w| > thr): +1 -> 0x3F80, -1 -> 0xBF80, 0 -> 0x0000 (exact bf16)
  return (fabsf(w) > thr) ? ((w > 0.0f) ? (unsigned short)0x3F80u
                                        : (unsigned short)0xBF80u)
                          : (unsigned short)0u;
}

__global__ void quant_w_kernel(const float4* __restrict__ W4,
                               unsigned short* __restrict__ Wq,
                               const double* __restrict__ sum_ptr, long long n8) {
  const double mean = *sum_ptr / (double)((long long)N_DIM * K_DIM);
  const float thr = (float)(0.7 * mean);
  const long long stride = (long long)gridDim.x * blockDim.x;
  for (long long i = (long long)blockIdx.x * blockDim.x + threadIdx.x; i < n8; i += stride) {
    float4 a = W4[2 * i];
    float4 b = W4[2 * i + 1];
    u16x8 q;
    q[0] = tern_bf16(a.x, thr); q[1] = tern_bf16(a.y, thr);
    q[2] = tern_bf16(a.z, thr); q[3] = tern_bf16(a.w, thr);
    q[4] = tern_bf16(b.x, thr); q[5] = tern_bf16(b.y, thr);
    q[6] = tern_bf16(b.z, thr); q[7] = tern_bf16(b.w, thr);
    *(u16x8*)(Wq + i * 8) = q;
  }
}

// ---------- kernel 3: x f32 -> bf16 (round-to-nearest-even) ----------
__device__ __forceinline__ unsigned short f32_to_bf16_rne(float f) {
  unsigned int u = __float_as_uint(f);
  u += 0x7FFFu + ((u >> 16) & 1u);
  return (unsigned short)(u >> 16);
}

__global__ void cvt_x_kernel(const float4* __restrict__ X4,
                             unsigned short* __restrict__ Xb, long long n8) {
  const long long stride = (long long)gridDim.x * blockDim.x;
  for (long long i = (long long)blockIdx.x * blockDim.x + threadIdx.x; i < n8; i += stride) {
    float4 a = X4[2 * i];
    float4 b = X4[2 * i + 1];
    u16x8 q;
    q[0] = f32_to_bf16_rne(a.x); q[1] = f32_to_bf16_rne(a.y);
    q[2] = f32_to_bf16_rne(a.z); q[3] = f32_to_bf16_rne(a.w);
    q[4] = f32_to_bf16_rne(b.x); q[5] = f32_to_bf16_rne(b.y);
    q[6] = f32_to_bf16_rne(b.z); q[7] = f32_to_bf16_rne(b.w);
    *(u16x8*)(Xb + i * 8) = q;
  }
}

// ---------- kernel 4: bf16 GEMM, C[m][n] = sum_k A[m][k]*B[n][k]  (m97 structure) ----------
#define BM 128
#define BN 128
#define BK 64

__global__ __launch_bounds__(256) void gemm_bt_kernel(
    const unsigned short* __restrict__ A,   // [M][K] bf16 bits
    const unsigned short* __restrict__ B,   // [N][K] bf16 bits (ternary)
    float* __restrict__ C,                  // [M][N] f32
    const float* __restrict__ scale_ptr) {
  constexpr int M = M_ROWS, N = N_DIM, K = K_DIM;
  __shared__ __align__(16) unsigned short As[BM * BK];
  __shared__ __align__(16) unsigned short Bs[BN * BK];

  const int tid = threadIdx.x;
  const int wave = tid >> 6;
  const int lane = tid & 63;

  // XCD-aware bijective swizzle (nwg % 8 == 0 here)
  const int nbm = M / BM;                  // 128
  const int nwg = nbm * (N / BN);          // 16384
  const int wg = (blockIdx.x & 7) * (nwg >> 3) + (blockIdx.x >> 3);
  const int bm = wg % nbm;                 // consecutive wg share bn -> B panel L2 reuse
  const int bn = wg / nbm;

  const int wr = wave >> 1;                // wave row 0..1 (64 rows each)
  const int wc = wave & 1;                 // wave col 0..1 (64 cols each)

  // staging: each global_load_lds stages 1024B = 8 rows x 128B; 16 chunks per tile
  const int strow = lane >> 3;             // row within chunk 0..7
  const int stcol = (lane & 7) * 8;        // element col within BK (16B per lane)

  const unsigned short* Ag = A + (size_t)(bm * BM) * K;
  const unsigned short* Bg = B + (size_t)(bn * BN) * K;

  f32x4 acc[4][4] = {};

  for (int k0 = 0; k0 < K; k0 += BK) {
#pragma unroll
    for (int i = 0; i < 4; ++i) {
      const int chunk = wave * 4 + i;
      const int row = chunk * 8 + strow;
      __builtin_amdgcn_global_load_lds(
          (__attribute__((address_space(1))) void*)(Ag + (size_t)row * K + k0 + stcol),
          (__attribute__((address_space(3))) void*)(As + chunk * 512), 16, 0, 0);
    }
#pragma unroll
    for (int i = 0; i < 4; ++i) {
      const int chunk = wave * 4 + i;
      const int row = chunk * 8 + strow;
      __builtin_amdgcn_global_load_lds(
          (__attribute__((address_space(1))) void*)(Bg + (size_t)row * K + k0 + stcol),
          (__attribute__((address_space(3))) void*)(Bs + chunk * 512), 16, 0, 0);
    }
    __syncthreads();

#pragma unroll
    for (int kk = 0; kk < BK; kk += 32) {
      bf16x8 af[4], bq[4];
#pragma unroll
      for (int m = 0; m < 4; ++m)
        af[m] = *(const bf16x8*)(As + (wr * 64 + m * 16 + (lane & 15)) * BK + kk + (lane >> 4) * 8);
#pragma unroll
      for (int n = 0; n < 4; ++n)
        bq[n] = *(const bf16x8*)(Bs + (wc * 64 + n * 16 + (lane & 15)) * BK + kk + (lane >> 4) * 8);
#pragma unroll
      for (int m = 0; m < 4; ++m)
#pragma unroll
        for (int n = 0; n < 4; ++n)
          acc[m][n] = __builtin_amdgcn_mfma_f32_16x16x32_bf16(af[m], bq[n], acc[m][n], 0, 0, 0);
    }
    __syncthreads();
  }

  const float scale = *scale_ptr;
  const int crow0 = bm * BM + wr * 64;
  const int ccol0 = bn * BN + wc * 64;
#pragma unroll
  for (int m = 0; m < 4; ++m)
#pragma unroll
    for (int n = 0; n < 4; ++n)
#pragma unroll
      for (int j = 0; j < 4; ++j) {
        // C/D layout (m89-verified): col = lane&15, row = (lane>>4)*4 + j
        const int row = crow0 + m * 16 + (lane >> 4) * 4 + j;
        const int col = ccol0 + n * 16 + (lane & 15);
        C[(size_t)row * N + col] = acc[m][n][j] * scale;
      }
}

extern "C" void kernel_launch(void* const* d_in, const int* in_sizes, int n_in,
                              void* d_out, int out_size, void* d_ws, size_t ws_size,
                              hipStream_t stream) {
  (void)in_sizes; (void)n_in; (void)out_size; (void)ws_size;
  const float* x = (const float*)d_in[0];
  const float* w = (const float*)d_in[1];
  const float* scale = (const float*)d_in[2];
  float* out = (float*)d_out;

  // workspace layout:
  //   [0, 16384)                       : 2048 double partials
  //   [16384, 16392)                   : total |W| sum (double)
  //   [32768, 32768+2*N*K)             : W quantized, bf16
  //   [32768+2*N*K, +2*M*K)            : x as bf16
  char* ws = (char*)d_ws;
  double* part = (double*)ws;
  double* sum = (double*)(ws + 16384);
  unsigned short* Wq = (unsigned short*)(ws + 32768);
  unsigned short* Xb = (unsigned short*)(ws + 32768 + (size_t)N_DIM * K_DIM * 2);

  const long long nW = (long long)N_DIM * K_DIM;   // 67108864
  const long long nX = (long long)M_ROWS * K_DIM;  // 67108864

  absum_part_kernel<<<RED_BLOCKS, 256, 0, stream>>>((const float4*)w, part, nW / 4);
  reduce_sum_kernel<<<1, 256, 0, stream>>>(part, sum, RED_BLOCKS);
  quant_w_kernel<<<2048, 256, 0, stream>>>((const float4*)w, Wq, sum, nW / 8);
  cvt_x_kernel<<<2048, 256, 0, stream>>>((const float4*)x, Xb, nX / 8);

  const int nblocks = (M_ROWS / BM) * (N_DIM / BN);  // 16384
  gemm_bt_kernel<<<nblocks, 256, 0, stream>>>(Xb, Wq, out, scale);
}

// Round 2
// 2360.448 us; speedup vs baseline: 1.5021x; 1.5021x over previous
//
#include <hip/hip_runtime.h>
#include <hip/hip_bf16.h>
#include <stdint.h>

// BitLinear: out = x @ (sign(W)*(|W|>0.7*mean|W|)*scale)^T
// M=16384 (8*2048), K=4096, N=16384. All f32 in/out.
// Round 2: 256x256 tile, BK=64, 8 waves, phase-split schedule with
//   - T2 st-swizzled LDS (linear gload_lds dest + inverse-swizzled global src + swizzled ds_read)
//   - T3/T4 deep prefetch: all next-tile loads issued at phase 0, single vmcnt(0) at tile boundary
//   - T5 setprio around MFMA clusters
// Prep kernels (threshold / quantize / cast) byte-identical to round 1.

typedef __attribute__((ext_vector_type(8))) __bf16 bf16x8;
typedef __attribute__((ext_vector_type(4))) float f32x4;
typedef __attribute__((ext_vector_type(8))) unsigned short u16x8;

#define M_ROWS 16384
#define K_DIM  4096
#define N_DIM  16384

#define RED_BLOCKS 2048

// ---------- kernel 1a: per-block partial sums of |W| (deterministic) ----------
__global__ void absum_part_kernel(const float4* __restrict__ W4,
                                  double* __restrict__ part, long long n4) {
  double s = 0.0;
  const long long stride = (long long)gridDim.x * blockDim.x;
  for (long long i = (long long)blockIdx.x * blockDim.x + threadIdx.x; i < n4; i += stride) {
    float4 v = W4[i];
    s += (double)fabsf(v.x);
    s += (double)fabsf(v.y);
    s += (double)fabsf(v.z);
    s += (double)fabsf(v.w);
  }
  for (int o = 32; o > 0; o >>= 1) s += __shfl_down(s, o, 64);
  __shared__ double p[4];
  if ((threadIdx.x & 63) == 0) p[threadIdx.x >> 6] = s;
  __syncthreads();
  if (threadIdx.x == 0) part[blockIdx.x] = p[0] + p[1] + p[2] + p[3];
}

// ---------- kernel 1b: reduce partials -> total sum ----------
__global__ void reduce_sum_kernel(const double* __restrict__ part,
                                  double* __restrict__ sum, int n) {
  double s = 0.0;
  for (int i = threadIdx.x; i < n; i += blockDim.x) s += part[i];
  for (int o = 32; o > 0; o >>= 1) s += __shfl_down(s, o, 64);
  __shared__ double p[4];
  if ((threadIdx.x & 63) == 0) p[threadIdx.x >> 6] = s;
  __syncthreads();
  if (threadIdx.x == 0) *sum = p[0] + p[1] + p[2] + p[3];
}

// ---------- kernel 2: ternary-quantize W -> bf16 bit patterns ----------
__device__ __forceinline__ unsigned short tern_bf16(float w, float thr) {
  return (fabsf(w) > thr) ? ((w > 0.0f) ? (unsigned short)0x3F80u
                                        : (unsigned short)0xBF80u)
                          : (unsigned short)0u;
}

__global__ void quant_w_kernel(const float4* __restrict__ W4,
                               unsigned short* __restrict__ Wq,
                               const double* __restrict__ sum_ptr, long long n8) {
  const double mean = *sum_ptr / (double)((long long)N_DIM * K_DIM);
  const float thr = (float)(0.7 * mean);
  const long long stride = (long long)gridDim.x * blockDim.x;
  for (long long i = (long long)blockIdx.x * blockDim.x + threadIdx.x; i < n8; i += stride) {
    float4 a = W4[2 * i];
    float4 b = W4[2 * i + 1];
    u16x8 q;
    q[0] = tern_bf16(a.x, thr); q[1] = tern_bf16(a.y, thr);
    q[2] = tern_bf16(a.z, thr); q[3] = tern_bf16(a.w, thr);
    q[4] = tern_bf16(b.x, thr); q[5] = tern_bf16(b.y, thr);
    q[6] = tern_bf16(b.z, thr); q[7] = tern_bf16(b.w, thr);
    *(u16x8*)(Wq + i * 8) = q;
  }
}

// ---------- kernel 3: x f32 -> bf16 (RNE) ----------
__device__ __forceinline__ unsigned short f32_to_bf16_rne(float f) {
  unsigned int u = __float_as_uint(f);
  u += 0x7FFFu + ((u >> 16) & 1u);
  return (unsigned short)(u >> 16);
}

__global__ void cvt_x_kernel(const float4* __restrict__ X4,
                             unsigned short* __restrict__ Xb, long long n8) {
  const long long stride = (long long)gridDim.x * blockDim.x;
  for (long long i = (long long)blockIdx.x * blockDim.x + threadIdx.x; i < n8; i += stride) {
    float4 a = X4[2 * i];
    float4 b = X4[2 * i + 1];
    u16x8 q;
    q[0] = f32_to_bf16_rne(a.x); q[1] = f32_to_bf16_rne(a.y);
    q[2] = f32_to_bf16_rne(a.z); q[3] = f32_to_bf16_rne(a.w);
    q[4] = f32_to_bf16_rne(b.x); q[5] = f32_to_bf16_rne(b.y);
    q[6] = f32_to_bf16_rne(b.z); q[7] = f32_to_bf16_rne(b.w);
    *(u16x8*)(Xb + i * 8) = q;
  }
}

// ---------- kernel 4: bf16 GEMM, 256x256 tile, phase-split schedule ----------
#define BM 256
#define BN 256
#define BK 64
#define NT (K_DIM / BK)   // 64

__global__ __launch_bounds__(512, 2) void gemm_bt_kernel(
    const unsigned short* __restrict__ A,   // [M][K] bf16 bits
    const unsigned short* __restrict__ B,   // [N][K] bf16 bits (ternary)
    float* __restrict__ C,                  // [M][N] f32
    const float* __restrict__ scale_ptr) {
  constexpr int K = K_DIM, N = N_DIM;
  // [buf][A=0/B=1][row][col] bf16: 2*2*256*64*2B = 128 KiB
  __shared__ __align__(16) unsigned short lds[2][2][BM][BK];

  const int tid = threadIdx.x;
  const int wave = tid >> 6;      // 0..7
  const int lane = tid & 63;

  // XCD-aware bijective swizzle (nwg = 4096, %8 == 0)
  const int nbm = M_ROWS / BM;    // 64
  const int nwg = nbm * (N / BN); // 4096
  const int wg = (blockIdx.x & 7) * (nwg >> 3) + (blockIdx.x >> 3);
  const int bm = wg % nbm;        // consecutive wg share bn -> B panel L2 reuse
  const int bn = wg / nbm;

  const int wr = wave >> 2;       // 0..1  (128 rows each)
  const int wc = wave & 3;        // 0..3  (64 cols each)

  const unsigned short* Ag = A + (size_t)(bm * BM) * K;
  const unsigned short* Bg = B + (size_t)(bn * BN) * K;

  // --- staging geometry: chunk = 8 rows x 128B = 1024B, one gload_lds per wave.
  // LDS dest is linear (base + lane*16). Global source col is INVERSE-swizzled so
  // that LDS(r, c') holds global(r, c' ^ ((r&7)<<4)) [bytes].
  const int strow = lane >> 3;                        // row within chunk 0..7
  const int stcols = ((lane & 7) ^ strow) << 3;       // source col in shorts (swizzled)

  // --- fragment-read swizzle: logical short-col = kk*32 + (lane>>4)*8;
  // swizzled short-col = logical ^ ((row&7)<<3), with row&7 == lane&7.
  const int frow = lane & 15;
  const int sw3 = (lane & 7) << 3;

  f32x4 acc[8][4] = {};

  // ---------- prologue: stage tile 0 into buf 0 ----------
  {
#pragma unroll
    for (int i = 0; i < 4; ++i) {
      const int j = wave * 4 + i;
      const int row = j * 8 + strow;
      __builtin_amdgcn_global_load_lds(
          (__attribute__((address_space(1))) void*)(Ag + (size_t)row * K + stcols),
          (__attribute__((address_space(3))) void*)(&lds[0][0][j * 8][0]), 16, 0, 0);
      __builtin_amdgcn_global_load_lds(
          (__attribute__((address_space(1))) void*)(Bg + (size_t)row * K + stcols),
          (__attribute__((address_space(3))) void*)(&lds[0][1][j * 8][0]), 16, 0, 0);
    }
    asm volatile("s_waitcnt vmcnt(0)" ::: "memory");
    __builtin_amdgcn_s_barrier();
  }

  for (int t = 0; t < NT; ++t) {
    const int q = t & 1;
    const unsigned short* As_ = &lds[q][0][0][0];
    const unsigned short* Bs_ = &lds[q][1][0][0];

    bf16x8 bf[4][2];   // all B frags for this wave (persist across phases)
    bf16x8 af[2][2];   // A frags for current phase

    // ---------------- phase 0 ----------------
    // ds_read: all 8 B frags + A frags m=0,1 (12 x ds_read_b128)
#pragma unroll
    for (int n = 0; n < 4; ++n)
#pragma unroll
      for (int kk = 0; kk < 2; ++kk)
        bf[n][kk] = *(const bf16x8*)(Bs_ + (wc * 64 + n * 16 + frow) * BK +
                                     (((kk << 5) + ((lane >> 4) << 3)) ^ sw3));
#pragma unroll
    for (int m = 0; m < 2; ++m)
#pragma unroll
      for (int kk = 0; kk < 2; ++kk)
        af[m][kk] = *(const bf16x8*)(As_ + (wr * 128 + m * 16 + frow) * BK +
                                     (((kk << 5) + ((lane >> 4) << 3)) ^ sw3));

    // issue ALL next-tile stages now (land by the tile-boundary vmcnt, ~3 phases later)
    if (t + 1 < NT) {
      const int k0n = (t + 1) * BK;
      unsigned short* Ad = &lds[q ^ 1][0][0][0];
      unsigned short* Bd = &lds[q ^ 1][1][0][0];
#pragma unroll
      for (int i = 0; i < 4; ++i) {
        const int j = wave * 4 + i;
        const int row = j * 8 + strow;
        __builtin_amdgcn_global_load_lds(
            (__attribute__((address_space(1))) void*)(Ag + (size_t)row * K + k0n + stcols),
            (__attribute__((address_space(3))) void*)(Ad + j * 8 * BK), 16, 0, 0);
        __builtin_amdgcn_global_load_lds(
            (__attribute__((address_space(1))) void*)(Bg + (size_t)row * K + k0n + stcols),
            (__attribute__((address_space(3))) void*)(Bd + j * 8 * BK), 16, 0, 0);
      }
      __builtin_amdgcn_sched_barrier(0);  // pin issues early; don't sink below MFMA
    }

    __builtin_amdgcn_s_barrier();          // raw barrier: no vmcnt drain
    __builtin_amdgcn_s_setprio(1);
#pragma unroll
    for (int m = 0; m < 2; ++m)
#pragma unroll
      for (int n = 0; n < 4; ++n)
#pragma unroll
        for (int kk = 0; kk < 2; ++kk)
          acc[m][n] = __builtin_amdgcn_mfma_f32_16x16x32_bf16(af[m][kk], bf[n][kk],
                                                              acc[m][n], 0, 0, 0);
    __builtin_amdgcn_s_setprio(0);
    __builtin_amdgcn_s_barrier();

    // ---------------- phases 1..3 ----------------
#pragma unroll
    for (int p = 1; p < 4; ++p) {
#pragma unroll
      for (int m = 0; m < 2; ++m)
#pragma unroll
        for (int kk = 0; kk < 2; ++kk)
          af[m][kk] = *(const bf16x8*)(As_ + (wr * 128 + (2 * p + m) * 16 + frow) * BK +
                                       (((kk << 5) + ((lane >> 4) << 3)) ^ sw3));
      __builtin_amdgcn_s_barrier();
      __builtin_amdgcn_s_setprio(1);
#pragma unroll
      for (int m = 0; m < 2; ++m)
#pragma unroll
        for (int n = 0; n < 4; ++n)
#pragma unroll
          for (int kk = 0; kk < 2; ++kk)
            acc[2 * p + m][n] = __builtin_amdgcn_mfma_f32_16x16x32_bf16(
                af[m][kk], bf[n][kk], acc[2 * p + m][n], 0, 0, 0);
      __builtin_amdgcn_s_setprio(0);
      if (p == 3) {
        // tile boundary: our DMA for tile t+1 landed + all our LDS reads done,
        // THEN barrier -> next tile's reads/overwrites are safe for all waves.
        asm volatile("s_waitcnt vmcnt(0) lgkmcnt(0)" ::: "memory");
      }
      __builtin_amdgcn_s_barrier();
    }
  }

  // ---------------- epilogue ----------------
  const float scale = *scale_ptr;
  const int crow0 = bm * BM + wr * 128;
  const int ccol0 = bn * BN + wc * 64;
#pragma unroll
  for (int m = 0; m < 8; ++m)
#pragma unroll
    for (int n = 0; n < 4; ++n)
#pragma unroll
      for (int j = 0; j < 4; ++j) {
        // C/D layout (m89-verified): col = lane&15, row = (lane>>4)*4 + j
        const int row = crow0 + m * 16 + ((lane >> 4) << 2) + j;
        const int col = ccol0 + n * 16 + (lane & 15);
        C[(size_t)row * N + col] = acc[m][n][j] * scale;
      }
}

extern "C" void kernel_launch(void* const* d_in, const int* in_sizes, int n_in,
                              void* d_out, int out_size, void* d_ws, size_t ws_size,
                              hipStream_t stream) {
  (void)in_sizes; (void)n_in; (void)out_size; (void)ws_size;
  const float* x = (const float*)d_in[0];
  const float* w = (const float*)d_in[1];
  const float* scale = (const float*)d_in[2];
  float* out = (float*)d_out;

  char* ws = (char*)d_ws;
  double* part = (double*)ws;
  double* sum = (double*)(ws + 16384);
  unsigned short* Wq = (unsigned short*)(ws + 32768);
  unsigned short* Xb = (unsigned short*)(ws + 32768 + (size_t)N_DIM * K_DIM * 2);

  const long long nW = (long long)N_DIM * K_DIM;   // 67108864
  const long long nX = (long long)M_ROWS * K_DIM;  // 67108864

  absum_part_kernel<<<RED_BLOCKS, 256, 0, stream>>>((const float4*)w, part, nW / 4);
  reduce_sum_kernel<<<1, 256, 0, stream>>>(part, sum, RED_BLOCKS);
  quant_w_kernel<<<2048, 256, 0, stream>>>((const float4*)w, Wq, sum, nW / 8);
  cvt_x_kernel<<<2048, 256, 0, stream>>>((const float4*)x, Xb, nX / 8);

  const int nblocks = (M_ROWS / BM) * (N_DIM / BN);  // 4096
  gemm_bt_kernel<<<nblocks, 512, 0, stream>>>(Xb, Wq, out, scale);
}

// Round 3
// 2315.632 us; speedup vs baseline: 1.5311x; 1.0194x over previous
//
#include <hip/hip_runtime.h>
#include <hip/hip_bf16.h>
#include <stdint.h>

// BitLinear: out = x @ (sign(W)*(|W|>0.7*mean|W|)*scale)^T
// M=16384 (8*2048), K=4096, N=16384. All f32 in/out.
// Round 3: 256x256 tile, BK=32, FOUR LDS buffers (4x32KB=128KiB), one barrier +
// one COUNTED vmcnt(8) per K-tile (T4): stage(t+3) issues while computing t, so
// tile t+1's loads are awaited with 8 younger loads still in flight. Never
// drains vmcnt to 0 in the main loop. T2 swizzle: slot' = (slot + (row>>1))&3
// (2-way max on 64B rows), inverse-applied at the global source (rule 21).
// Prep kernels byte-identical to rounds 1-2.

typedef __attribute__((ext_vector_type(8))) __bf16 bf16x8;
typedef __attribute__((ext_vector_type(4))) float f32x4;
typedef __attribute__((ext_vector_type(8))) unsigned short u16x8;

#define M_ROWS 16384
#define K_DIM  4096
#define N_DIM  16384

#define RED_BLOCKS 2048

// ---------- kernel 1a: per-block partial sums of |W| (deterministic) ----------
__global__ void absum_part_kernel(const float4* __restrict__ W4,
                                  double* __restrict__ part, long long n4) {
  double s = 0.0;
  const long long stride = (long long)gridDim.x * blockDim.x;
  for (long long i = (long long)blockIdx.x * blockDim.x + threadIdx.x; i < n4; i += stride) {
    float4 v = W4[i];
    s += (double)fabsf(v.x);
    s += (double)fabsf(v.y);
    s += (double)fabsf(v.z);
    s += (double)fabsf(v.w);
  }
  for (int o = 32; o > 0; o >>= 1) s += __shfl_down(s, o, 64);
  __shared__ double p[4];
  if ((threadIdx.x & 63) == 0) p[threadIdx.x >> 6] = s;
  __syncthreads();
  if (threadIdx.x == 0) part[blockIdx.x] = p[0] + p[1] + p[2] + p[3];
}

// ---------- kernel 1b: reduce partials -> total sum ----------
__global__ void reduce_sum_kernel(const double* __restrict__ part,
                                  double* __restrict__ sum, int n) {
  double s = 0.0;
  for (int i = threadIdx.x; i < n; i += blockDim.x) s += part[i];
  for (int o = 32; o > 0; o >>= 1) s += __shfl_down(s, o, 64);
  __shared__ double p[4];
  if ((threadIdx.x & 63) == 0) p[threadIdx.x >> 6] = s;
  __syncthreads();
  if (threadIdx.x == 0) *sum = p[0] + p[1] + p[2] + p[3];
}

// ---------- kernel 2: ternary-quantize W -> bf16 bit patterns ----------
__device__ __forceinline__ unsigned short tern_bf16(float w, float thr) {
  return (fabsf(w) > thr) ? ((w > 0.0f) ? (unsigned short)0x3F80u
                                        : (unsigned short)0xBF80u)
                          : (unsigned short)0u;
}

__global__ void quant_w_kernel(const float4* __restrict__ W4,
                               unsigned short* __restrict__ Wq,
                               const double* __restrict__ sum_ptr, long long n8) {
  const double mean = *sum_ptr / (double)((long long)N_DIM * K_DIM);
  const float thr = (float)(0.7 * mean);
  const long long stride = (long long)gridDim.x * blockDim.x;
  for (long long i = (long long)blockIdx.x * blockDim.x + threadIdx.x; i < n8; i += stride) {
    float4 a = W4[2 * i];
    float4 b = W4[2 * i + 1];
    u16x8 q;
    q[0] = tern_bf16(a.x, thr); q[1] = tern_bf16(a.y, thr);
    q[2] = tern_bf16(a.z, thr); q[3] = tern_bf16(a.w, thr);
    q[4] = tern_bf16(b.x, thr); q[5] = tern_bf16(b.y, thr);
    q[6] = tern_bf16(b.z, thr); q[7] = tern_bf16(b.w, thr);
    *(u16x8*)(Wq + i * 8) = q;
  }
}

// ---------- kernel 3: x f32 -> bf16 (RNE) ----------
__device__ __forceinline__ unsigned short f32_to_bf16_rne(float f) {
  unsigned int u = __float_as_uint(f);
  u += 0x7FFFu + ((u >> 16) & 1u);
  return (unsigned short)(u >> 16);
}

__global__ void cvt_x_kernel(const float4* __restrict__ X4,
                             unsigned short* __restrict__ Xb, long long n8) {
  const long long stride = (long long)gridDim.x * blockDim.x;
  for (long long i = (long long)blockIdx.x * blockDim.x + threadIdx.x; i < n8; i += stride) {
    float4 a = X4[2 * i];
    float4 b = X4[2 * i + 1];
    u16x8 q;
    q[0] = f32_to_bf16_rne(a.x); q[1] = f32_to_bf16_rne(a.y);
    q[2] = f32_to_bf16_rne(a.z); q[3] = f32_to_bf16_rne(a.w);
    q[4] = f32_to_bf16_rne(b.x); q[5] = f32_to_bf16_rne(b.y);
    q[6] = f32_to_bf16_rne(b.z); q[7] = f32_to_bf16_rne(b.w);
    *(u16x8*)(Xb + i * 8) = q;
  }
}

// ---------- kernel 4: bf16 GEMM, 256x256 tile, BK=32, 4-deep counted-vmcnt ----------
#define BM 256
#define BN 256
#define BK 32
#define NT (K_DIM / BK)   // 128

__global__ __launch_bounds__(512, 2) void gemm_bt_kernel(
    const unsigned short* __restrict__ A,   // [M][K] bf16 bits
    const unsigned short* __restrict__ B,   // [N][K] bf16 bits (ternary)
    float* __restrict__ C,                  // [M][N] f32
    const float* __restrict__ scale_ptr) {
  constexpr int K = K_DIM, N = N_DIM;
  // 4 rotating buffers x {A,B} x 256 rows x 32 shorts = 128 KiB
  __shared__ __align__(16) unsigned short lds[4][2][BM][BK];

  const int tid = threadIdx.x;
  const int wave = tid >> 6;      // 0..7
  const int lane = tid & 63;

  // XCD-aware bijective swizzle (nwg = 4096, %8 == 0)
  const int nbm = M_ROWS / BM;    // 64
  const int nwg = nbm * (N / BN); // 4096
  const int wg = (blockIdx.x & 7) * (nwg >> 3) + (blockIdx.x >> 3);
  const int bm = wg % nbm;        // consecutive wg share bn -> B panel L2 reuse
  const int bn = wg / nbm;

  const int wr = wave >> 2;       // 0..1  (128 rows each)
  const int wc = wave & 3;        // 0..3  (64 cols each)

  const unsigned short* Ag = A + (size_t)(bm * BM) * K;
  const unsigned short* Bg = B + (size_t)(bn * BN) * K;

  // --- staging: chunk = 16 rows x 64B = 1024B, one gload_lds per wave-instr.
  // LDS dest linear: lane l -> row l>>2, slot l&3 (slot = 16B). Bank swizzle:
  // LDS[row][slot'] = G[row][(slot' - ((row>>1)&3)) & 3]. Inverse at source:
  const int strow = lane >> 2;                               // row in chunk 0..15
  const int scol = ((((lane & 3) - (lane >> 3)) & 3) << 3);  // src col in shorts

  // --- fragment read: logical slot = lane>>4; row = base16 + (lane&15)
  // read slot' = (logical + ((lane&15)>>1)) & 3  -> 2-way bank aliasing (free)
  const int frow = lane & 15;
  const int fsw = ((((lane >> 4) + ((lane & 15) >> 1)) & 3) << 3);  // shorts

#define STAGE(u)                                                                     \
  {                                                                                  \
    const int kk0_ = (u) * BK;                                                       \
    unsigned short* Ab_ = &lds[(u) & 3][0][0][0];                                    \
    unsigned short* Bb_ = &lds[(u) & 3][1][0][0];                                    \
    _Pragma("unroll")                                                                \
    for (int i_ = 0; i_ < 2; ++i_) {                                                 \
      const int ch_ = wave * 2 + i_;                                                 \
      const int row_ = ch_ * 16 + strow;                                             \
      __builtin_amdgcn_global_load_lds(                                              \
          (__attribute__((address_space(1))) void*)(Ag + (size_t)row_ * K + kk0_ + scol), \
          (__attribute__((address_space(3))) void*)(Ab_ + ch_ * 16 * BK), 16, 0, 0); \
      __builtin_amdgcn_global_load_lds(                                              \
          (__attribute__((address_space(1))) void*)(Bg + (size_t)row_ * K + kk0_ + scol), \
          (__attribute__((address_space(3))) void*)(Bb_ + ch_ * 16 * BK), 16, 0, 0); \
    }                                                                                \
  }

  f32x4 acc[8][4] = {};

  // ---------- prologue: stage tiles 0,1,2 (12 loads/wave in flight) ----------
  STAGE(0);
  STAGE(1);
  STAGE(2);
  asm volatile("s_waitcnt vmcnt(8)" ::: "memory");  // tile 0 landed; 1,2 in flight
  __builtin_amdgcn_s_barrier();
  __builtin_amdgcn_sched_barrier(0);

  for (int t = 0; t < NT; ++t) {
    // stage tile t+3 into buf (t+3)&3 == (t-1)&3 (freed by last iter's barrier)
    if (t + 3 < NT) STAGE(t + 3);

    const unsigned short* As_ = &lds[t & 3][0][0][0];
    const unsigned short* Bs_ = &lds[t & 3][1][0][0];

    bf16x8 bf[4], af[8];
#pragma unroll
    for (int n = 0; n < 4; ++n)
      bf[n] = *(const bf16x8*)(Bs_ + (wc * 64 + n * 16 + frow) * BK + fsw);
#pragma unroll
    for (int m = 0; m < 8; ++m)
      af[m] = *(const bf16x8*)(As_ + (wr * 128 + m * 16 + frow) * BK + fsw);

    __builtin_amdgcn_s_setprio(1);
#pragma unroll
    for (int m = 0; m < 8; ++m)
#pragma unroll
      for (int n = 0; n < 4; ++n)
        acc[m][n] = __builtin_amdgcn_mfma_f32_16x16x32_bf16(af[m], bf[n], acc[m][n], 0, 0, 0);
    __builtin_amdgcn_s_setprio(0);

    // pin MFMAs (and their lgkm waits) above the checkpoint
    __builtin_amdgcn_sched_barrier(0);
    // counted wait: tile t+1 landed; stages t+2, t+3 stay in flight (never 0
    // in steady state). Tail peels the count down.
    if (t < NT - 3) {
      asm volatile("s_waitcnt vmcnt(8)" ::: "memory");
    } else if (t == NT - 3) {
      asm volatile("s_waitcnt vmcnt(4)" ::: "memory");
    } else if (t == NT - 2) {
      asm volatile("s_waitcnt vmcnt(0)" ::: "memory");
    }
    if (t + 1 < NT) __builtin_amdgcn_s_barrier();
    __builtin_amdgcn_sched_barrier(0);
  }
#undef STAGE

  // ---------------- epilogue ----------------
  const float scale = *scale_ptr;
  const int crow0 = bm * BM + wr * 128;
  const int ccol0 = bn * BN + wc * 64;
#pragma unroll
  for (int m = 0; m < 8; ++m)
#pragma unroll
    for (int n = 0; n < 4; ++n)
#pragma unroll
      for (int j = 0; j < 4; ++j) {
        // C/D layout (m89-verified): col = lane&15, row = (lane>>4)*4 + j
        const int row = crow0 + m * 16 + ((lane >> 4) << 2) + j;
        const int col = ccol0 + n * 16 + (lane & 15);
        C[(size_t)row * N + col] = acc[m][n][j] * scale;
      }
}

extern "C" void kernel_launch(void* const* d_in, const int* in_sizes, int n_in,
                              void* d_out, int out_size, void* d_ws, size_t ws_size,
                              hipStream_t stream) {
  (void)in_sizes; (void)n_in; (void)out_size; (void)ws_size;
  const float* x = (const float*)d_in[0];
  const float* w = (const float*)d_in[1];
  const float* scale = (const float*)d_in[2];
  float* out = (float*)d_out;

  char* ws = (char*)d_ws;
  double* part = (double*)ws;
  double* sum = (double*)(ws + 16384);
  unsigned short* Wq = (unsigned short*)(ws + 32768);
  unsigned short* Xb = (unsigned short*)(ws + 32768 + (size_t)N_DIM * K_DIM * 2);

  const long long nW = (long long)N_DIM * K_DIM;   // 67108864
  const long long nX = (long long)M_ROWS * K_DIM;  // 67108864

  absum_part_kernel<<<RED_BLOCKS, 256, 0, stream>>>((const float4*)w, part, nW / 4);
  reduce_sum_kernel<<<1, 256, 0, stream>>>(part, sum, RED_BLOCKS);
  quant_w_kernel<<<2048, 256, 0, stream>>>((const float4*)w, Wq, sum, nW / 8);
  cvt_x_kernel<<<2048, 256, 0, stream>>>((const float4*)x, Xb, nX / 8);

  const int nblocks = (M_ROWS / BM) * (N_DIM / BN);  // 4096
  gemm_bt_kernel<<<nblocks, 512, 0, stream>>>(Xb, Wq, out, scale);
}

// Round 4
// 2222.706 us; speedup vs baseline: 1.5952x; 1.0418x over previous
//
#include <hip/hip_runtime.h>
#include <hip/hip_bf16.h>
#include <stdint.h>

// BitLinear: out = x @ (sign(W)*(|W|>0.7*mean|W|)*scale)^T
// M=16384 (8*2048), K=4096, N=16384. All f32 in/out.
// Round 4: register-fragment double-buffer. While MFMA(t) executes, the 12
// ds_read_b128 for tile t+1 drain in the LDS pipe (no register dep). One
// barrier + one counted vmcnt(8) per K-tile; lgkmcnt(0) before the barrier
// closes the frag-read-vs-DMA-overwrite race. 4 LDS buffers, stage t+3 ahead.
// T2 swizzle + accumulation order byte-identical to round 3.

typedef __attribute__((ext_vector_type(8))) __bf16 bf16x8;
typedef __attribute__((ext_vector_type(4))) float f32x4;
typedef __attribute__((ext_vector_type(8))) unsigned short u16x8;

#define M_ROWS 16384
#define K_DIM  4096
#define N_DIM  16384

#define RED_BLOCKS 2048

// ---------- kernel 1a: per-block partial sums of |W| (deterministic) ----------
__global__ void absum_part_kernel(const float4* __restrict__ W4,
                                  double* __restrict__ part, long long n4) {
  double s = 0.0;
  const long long stride = (long long)gridDim.x * blockDim.x;
  for (long long i = (long long)blockIdx.x * blockDim.x + threadIdx.x; i < n4; i += stride) {
    float4 v = W4[i];
    s += (double)fabsf(v.x);
    s += (double)fabsf(v.y);
    s += (double)fabsf(v.z);
    s += (double)fabsf(v.w);
  }
  for (int o = 32; o > 0; o >>= 1) s += __shfl_down(s, o, 64);
  __shared__ double p[4];
  if ((threadIdx.x & 63) == 0) p[threadIdx.x >> 6] = s;
  __syncthreads();
  if (threadIdx.x == 0) part[blockIdx.x] = p[0] + p[1] + p[2] + p[3];
}

// ---------- kernel 1b: reduce partials -> total sum ----------
__global__ void reduce_sum_kernel(const double* __restrict__ part,
                                  double* __restrict__ sum, int n) {
  double s = 0.0;
  for (int i = threadIdx.x; i < n; i += blockDim.x) s += part[i];
  for (int o = 32; o > 0; o >>= 1) s += __shfl_down(s, o, 64);
  __shared__ double p[4];
  if ((threadIdx.x & 63) == 0) p[threadIdx.x >> 6] = s;
  __syncthreads();
  if (threadIdx.x == 0) *sum = p[0] + p[1] + p[2] + p[3];
}

// ---------- kernel 2: ternary-quantize W -> bf16 bit patterns ----------
__device__ __forceinline__ unsigned short tern_bf16(float w, float thr) {
  return (fabsf(w) > thr) ? ((w > 0.0f) ? (unsigned short)0x3F80u
                                        : (unsigned short)0xBF80u)
                          : (unsigned short)0u;
}

__global__ void quant_w_kernel(const float4* __restrict__ W4,
                               unsigned short* __restrict__ Wq,
                               const double* __restrict__ sum_ptr, long long n8) {
  const double mean = *sum_ptr / (double)((long long)N_DIM * K_DIM);
  const float thr = (float)(0.7 * mean);
  const long long stride = (long long)gridDim.x * blockDim.x;
  for (long long i = (long long)blockIdx.x * blockDim.x + threadIdx.x; i < n8; i += stride) {
    float4 a = W4[2 * i];
    float4 b = W4[2 * i + 1];
    u16x8 q;
    q[0] = tern_bf16(a.x, thr); q[1] = tern_bf16(a.y, thr);
    q[2] = tern_bf16(a.z, thr); q[3] = tern_bf16(a.w, thr);
    q[4] = tern_bf16(b.x, thr); q[5] = tern_bf16(b.y, thr);
    q[6] = tern_bf16(b.z, thr); q[7] = tern_bf16(b.w, thr);
    *(u16x8*)(Wq + i * 8) = q;
  }
}

// ---------- kernel 3: x f32 -> bf16 (RNE) ----------
__device__ __forceinline__ unsigned short f32_to_bf16_rne(float f) {
  unsigned int u = __float_as_uint(f);
  u += 0x7FFFu + ((u >> 16) & 1u);
  return (unsigned short)(u >> 16);
}

__global__ void cvt_x_kernel(const float4* __restrict__ X4,
                             unsigned short* __restrict__ Xb, long long n8) {
  const long long stride = (long long)gridDim.x * blockDim.x;
  for (long long i = (long long)blockIdx.x * blockDim.x + threadIdx.x; i < n8; i += stride) {
    float4 a = X4[2 * i];
    float4 b = X4[2 * i + 1];
    u16x8 q;
    q[0] = f32_to_bf16_rne(a.x); q[1] = f32_to_bf16_rne(a.y);
    q[2] = f32_to_bf16_rne(a.z); q[3] = f32_to_bf16_rne(a.w);
    q[4] = f32_to_bf16_rne(b.x); q[5] = f32_to_bf16_rne(b.y);
    q[6] = f32_to_bf16_rne(b.z); q[7] = f32_to_bf16_rne(b.w);
    *(u16x8*)(Xb + i * 8) = q;
  }
}

// ---------- kernel 4: bf16 GEMM, 256x256, BK=32, reg-frag double-buffer ----------
#define BM 256
#define BN 256
#define BK 32
#define NT (K_DIM / BK)   // 128

__global__ __launch_bounds__(512, 2) void gemm_bt_kernel(
    const unsigned short* __restrict__ A,   // [M][K] bf16 bits
    const unsigned short* __restrict__ B,   // [N][K] bf16 bits (ternary)
    float* __restrict__ C,                  // [M][N] f32
    const float* __restrict__ scale_ptr) {
  constexpr int K = K_DIM, N = N_DIM;
  // 4 rotating buffers x {A,B} x 256 rows x 32 shorts = 128 KiB
  __shared__ __align__(16) unsigned short lds[4][2][BM][BK];

  const int tid = threadIdx.x;
  const int wave = tid >> 6;      // 0..7
  const int lane = tid & 63;

  // XCD-aware bijective swizzle (nwg = 4096, %8 == 0)
  const int nbm = M_ROWS / BM;    // 64
  const int nwg = nbm * (N / BN); // 4096
  const int wg = (blockIdx.x & 7) * (nwg >> 3) + (blockIdx.x >> 3);
  const int bm = wg % nbm;        // consecutive wg share bn -> B panel L2 reuse
  const int bn = wg / nbm;

  const int wr = wave >> 2;       // 0..1  (128 rows each)
  const int wc = wave & 3;        // 0..3  (64 cols each)

  const unsigned short* Ag = A + (size_t)(bm * BM) * K;
  const unsigned short* Bg = B + (size_t)(bn * BN) * K;

  // staging: chunk = 16 rows x 64B; LDS dest linear; bank swizzle applied
  // inverse at the global source (rule 21), same constants as round 3.
  const int strow = lane >> 2;                               // row in chunk 0..15
  const int scol = ((((lane & 3) - (lane >> 3)) & 3) << 3);  // src col in shorts

  // fragment read: row = base16 + (lane&15); slot' = (lane>>4 + (row>>1)) & 3
  const int frow = lane & 15;
  const int fsw = ((((lane >> 4) + ((lane & 15) >> 1)) & 3) << 3);  // shorts

#define STAGE(u)                                                                     \
  {                                                                                  \
    const int kk0_ = (u) * BK;                                                       \
    unsigned short* Ab_ = &lds[(u) & 3][0][0][0];                                    \
    unsigned short* Bb_ = &lds[(u) & 3][1][0][0];                                    \
    _Pragma("unroll")                                                                \
    for (int i_ = 0; i_ < 2; ++i_) {                                                 \
      const int ch_ = wave * 2 + i_;                                                 \
      const int row_ = ch_ * 16 + strow;                                             \
      __builtin_amdgcn_global_load_lds(                                              \
          (__attribute__((address_space(1))) void*)(Ag + (size_t)row_ * K + kk0_ + scol), \
          (__attribute__((address_space(3))) void*)(Ab_ + ch_ * 16 * BK), 16, 0, 0); \
      __builtin_amdgcn_global_load_lds(                                              \
          (__attribute__((address_space(1))) void*)(Bg + (size_t)row_ * K + kk0_ + scol), \
          (__attribute__((address_space(3))) void*)(Bb_ + ch_ * 16 * BK), 16, 0, 0); \
    }                                                                                \
  }

  // read fragments of tile (u) into named frag arrays (static indexing only)
#define FRAGS(u, AF, BF)                                                             \
  {                                                                                  \
    const unsigned short* As_ = &lds[(u) & 3][0][0][0];                              \
    const unsigned short* Bs_ = &lds[(u) & 3][1][0][0];                              \
    _Pragma("unroll")                                                                \
    for (int n_ = 0; n_ < 4; ++n_)                                                   \
      BF[n_] = *(const bf16x8*)(Bs_ + (wc * 64 + n_ * 16 + frow) * BK + fsw);        \
    _Pragma("unroll")                                                                \
    for (int m_ = 0; m_ < 8; ++m_)                                                   \
      AF[m_] = *(const bf16x8*)(As_ + (wr * 128 + m_ * 16 + frow) * BK + fsw);       \
  }

#define MFMAS(AF, BF)                                                                \
  {                                                                                  \
    __builtin_amdgcn_s_setprio(1);                                                   \
    _Pragma("unroll")                                                                \
    for (int m_ = 0; m_ < 8; ++m_)                                                   \
      _Pragma("unroll")                                                              \
      for (int n_ = 0; n_ < 4; ++n_)                                                 \
        acc[m_][n_] = __builtin_amdgcn_mfma_f32_16x16x32_bf16(AF[m_], BF[n_],        \
                                                              acc[m_][n_], 0, 0, 0); \
    __builtin_amdgcn_s_setprio(0);                                                   \
  }

  // iter body: STAGE(t+3) -> counted vmcnt + lgkm drain -> barrier ->
  // frag-read(t+1) into NXT set -> MFMA(t) from CUR set (overlaps the reads)
#define ITER(T, CA, CB, NA, NB)                                                      \
  {                                                                                  \
    if ((T) + 3 < NT) STAGE((T) + 3);                                                \
    __builtin_amdgcn_sched_barrier(0);                                               \
    if ((T) + 1 < NT) {                                                              \
      if ((T) < NT - 3)                                                              \
        asm volatile("s_waitcnt vmcnt(8) lgkmcnt(0)" ::: "memory");                  \
      else if ((T) == NT - 3)                                                        \
        asm volatile("s_waitcnt vmcnt(4) lgkmcnt(0)" ::: "memory");                  \
      else                                                                           \
        asm volatile("s_waitcnt vmcnt(0) lgkmcnt(0)" ::: "memory");                  \
      __builtin_amdgcn_s_barrier();                                                  \
      __builtin_amdgcn_sched_barrier(0);                                             \
      FRAGS((T) + 1, NA, NB);                                                        \
      __builtin_amdgcn_sched_barrier(0);                                             \
    }                                                                                \
    MFMAS(CA, CB);                                                                   \
  }

  f32x4 acc[8][4] = {};
  bf16x8 af0[8], bf0[4], af1[8], bf1[4];

  // ---------- prologue: stage 0,1,2; read frags(0) into set0 ----------
  STAGE(0);
  STAGE(1);
  STAGE(2);
  asm volatile("s_waitcnt vmcnt(8)" ::: "memory");  // tile 0 landed; 1,2 in flight
  __builtin_amdgcn_s_barrier();
  __builtin_amdgcn_sched_barrier(0);
  FRAGS(0, af0, bf0);
  __builtin_amdgcn_sched_barrier(0);

  for (int t = 0; t < NT; t += 2) {
    ITER(t, af0, bf0, af1, bf1);
    ITER(t + 1, af1, bf1, af0, bf0);
  }
#undef ITER
#undef MFMAS
#undef FRAGS
#undef STAGE

  // ---------------- epilogue ----------------
  const float scale = *scale_ptr;
  const int crow0 = bm * BM + wr * 128;
  const int ccol0 = bn * BN + wc * 64;
#pragma unroll
  for (int m = 0; m < 8; ++m)
#pragma unroll
    for (int n = 0; n < 4; ++n)
#pragma unroll
      for (int j = 0; j < 4; ++j) {
        // C/D layout (m89-verified): col = lane&15, row = (lane>>4)*4 + j
        const int row = crow0 + m * 16 + ((lane >> 4) << 2) + j;
        const int col = ccol0 + n * 16 + (lane & 15);
        C[(size_t)row * N + col] = acc[m][n][j] * scale;
      }
}

extern "C" void kernel_launch(void* const* d_in, const int* in_sizes, int n_in,
                              void* d_out, int out_size, void* d_ws, size_t ws_size,
                              hipStream_t stream) {
  (void)in_sizes; (void)n_in; (void)out_size; (void)ws_size;
  const float* x = (const float*)d_in[0];
  const float* w = (const float*)d_in[1];
  const float* scale = (const float*)d_in[2];
  float* out = (float*)d_out;

  char* ws = (char*)d_ws;
  double* part = (double*)ws;
  double* sum = (double*)(ws + 16384);
  unsigned short* Wq = (unsigned short*)(ws + 32768);
  unsigned short* Xb = (unsigned short*)(ws + 32768 + (size_t)N_DIM * K_DIM * 2);

  const long long nW = (long long)N_DIM * K_DIM;   // 67108864
  const long long nX = (long long)M_ROWS * K_DIM;  // 67108864

  absum_part_kernel<<<RED_BLOCKS, 256, 0, stream>>>((const float4*)w, part, nW / 4);
  reduce_sum_kernel<<<1, 256, 0, stream>>>(part, sum, RED_BLOCKS);
  quant_w_kernel<<<2048, 256, 0, stream>>>((const float4*)w, Wq, sum, nW / 8);
  cvt_x_kernel<<<2048, 256, 0, stream>>>((const float4*)x, Xb, nX / 8);

  const int nblocks = (M_ROWS / BM) * (N_DIM / BN);  // 4096
  gemm_bt_kernel<<<nblocks, 512, 0, stream>>>(Xb, Wq, out, scale);
}